// Round 2
// baseline (397.380 us; speedup 1.0000x reference)
//
#include <hip/hip_runtime.h>

// IFOPooling: h_t = f_t * h_{t-1} + i_t * z_t along S (contiguous axis).
// Layout [B=16, H=1024, S=2048] fp32.
//
// One WAVE per (b,h) row, no LDS/barriers. The row is processed as 8 serial
// sub-blocks of 256 floats (lane l owns float4 at k*64+l -> coalesced 1 KiB
// wave loads). Per sub-block: load -> per-element prefix coefficients
// (A_j,B_j) -> 6-step wave shuffle scan of the lane-level op -> carry link ->
// replay via o_j = A_j*h_in + B_j -> nontemporal store.
//
// Round-1 post-mortem: keeping the whole row live (112+ regs) made the
// compiler re-load f/z/i from global inside the serial carry loop
// (VGPR_Count=56 proved it) -> 2x vmem traffic + dependent L2 latency in the
// serial chain. This version has per-stage live ranges of 8 floats plus a
// depth-3 load prefetch queue (~36 regs), so everything stays in registers
// and ~9 KB/wave of loads are continuously in flight.
// Nontemporal stores keep the write-once output from evicting input lines
// from L2/L3 (L3 residency currently serves ~half the input reads).

typedef float f32x4 __attribute__((ext_vector_type(4)));

constexpr int S_LEN  = 2048;
constexpr int WAVES  = 4;            // independent waves per block
constexpr int TPB    = 64 * WAVES;   // 256 threads
constexpr int K_SUB  = S_LEN / 256;  // 8 sub-blocks of 256 floats
constexpr int PRE    = 3;            // load prefetch depth (sub-blocks)

__global__ __launch_bounds__(TPB) void ifo_scan_kernel(
    const float* __restrict__ f,
    const float* __restrict__ z,
    const float* __restrict__ iin,
    float* __restrict__ out,
    int n_rows)
{
    const int lane = threadIdx.x & 63;
    const int wv   = threadIdx.x >> 6;
    const size_t row = (size_t)blockIdx.x * WAVES + wv;
    if (row >= (size_t)n_rows) return;
    const size_t base = row * S_LEN;

    const float4* __restrict__ F = reinterpret_cast<const float4*>(f   + base);
    const float4* __restrict__ Z = reinterpret_cast<const float4*>(z   + base);
    const float4* __restrict__ I = reinterpret_cast<const float4*>(iin + base);
    f32x4* __restrict__ O = reinterpret_cast<f32x4*>(out + base);

    // Prefetch queue: only PRE stages live at any time (static unroll ->
    // all indices compile-time -> registers, no scratch).
    float4 fq[K_SUB], zq[K_SUB], iq[K_SUB];
    #pragma unroll
    for (int k = 0; k < PRE; ++k) {
        fq[k] = F[k * 64 + lane];
        zq[k] = Z[k * 64 + lane];
        iq[k] = I[k * 64 + lane];
    }

    float carry = 0.0f;   // h entering current sub-block (wave-uniform)

    #pragma unroll
    for (int k = 0; k < K_SUB; ++k) {
        // Issue loads for stage k+PRE (independent of the carry chain).
        if (k + PRE < K_SUB) {
            fq[k + PRE] = F[(k + PRE) * 64 + lane];
            zq[k + PRE] = Z[(k + PRE) * 64 + lane];
            iq[k + PRE] = I[(k + PRE) * 64 + lane];
        }

        const float4 ffv = fq[k], zzv = zq[k], iiv = iq[k];
        const float x0 = iiv.x * zzv.x;
        const float x1 = iiv.y * zzv.y;
        const float x2 = iiv.z * zzv.z;
        const float x3 = iiv.w * zzv.w;

        // Per-element prefix coefficients within this lane's 4-chunk:
        // h_j = A_j * h_in + B_j  (h_in = h entering the chunk)
        const float A0 = ffv.x;      const float B0 = x0;
        const float A1 = ffv.y * A0; const float B1 = ffv.y * B0 + x1;
        const float A2 = ffv.z * A1; const float B2 = ffv.z * B1 + x2;
        const float A3 = ffv.w * A2; const float B3 = ffv.w * B2 + x3;

        // Wave inclusive scan of the lane-level op (A3,B3) under composition.
        float sa = A3, sb = B3;
        #pragma unroll
        for (int d = 1; d < 64; d <<= 1) {
            const float a_up = __shfl_up(sa, d);
            const float b_up = __shfl_up(sb, d);
            if (lane >= d) {
                sb = sa * b_up + sb;
                sa = sa * a_up;
            }
        }

        // h at the END of this lane's chunk, given carry into the sub-block.
        const float v = sa * carry + sb;
        float hin = __shfl_up(v, 1);      // h entering this lane's chunk
        if (lane == 0) hin = carry;

        f32x4 o;
        o.x = A0 * hin + B0;
        o.y = A1 * hin + B1;
        o.z = A2 * hin + B2;
        o.w = A3 * hin + B3;
        __builtin_nontemporal_store(o, O + k * 64 + lane);

        carry = __shfl(v, 63);            // carry into next sub-block
    }
}

extern "C" void kernel_launch(void* const* d_in, const int* in_sizes, int n_in,
                              void* d_out, int out_size, void* d_ws, size_t ws_size,
                              hipStream_t stream) {
    const float* f = (const float*)d_in[0];
    const float* z = (const float*)d_in[1];
    const float* i = (const float*)d_in[2];
    float* out = (float*)d_out;

    const int rows = out_size / S_LEN;                 // B*H = 16384
    const int grid = (rows + WAVES - 1) / WAVES;       // 4096 blocks
    ifo_scan_kernel<<<grid, TPB, 0, stream>>>(f, z, i, out, rows);
}

// Round 3
// 378.848 us; speedup vs baseline: 1.0489x; 1.0489x over previous
//
#include <hip/hip_runtime.h>

// IFOPooling: h_t = f_t * h_{t-1} + i_t * z_t along S (contiguous axis).
// Layout [B=16, H=1024, S=2048] fp32. One block per (b,h) row; work-efficient
// linear-recurrence scan: per-thread serial chunk -> wave DPP scan ->
// cross-wave LDS scan -> replay. Identical structure to the 142 µs round-0
// kernel EXCEPT the cross-lane scan:
//
//   round-0: 6 x 2 __shfl_up  = 12 dependent ds_bpermute (~120 cy each,
//            ~1440 cy of LDS-pipe latency per wave) + 2 more for the
//            exclusive shift.
//   now:     LLVM-style wave64 DPP scan (row_shr 1/2/4/8, row_bcast15
//            mask 0xa, row_bcast31 mask 0xc) + wave_shr1 exclusive shift.
//            All VALU, ~4 cy dep latency each; identity-fill via
//            update_dpp(old=identity) removes the lane>=d predication.
//
// The affine op (A,B) composes as: B = A*B_up + B; A = A*A_up, with
// identity (1,0) — update_dpp's `old` operand supplies the identity for
// shifted-out / masked lanes.

constexpr int S_LEN = 2048;
constexpr int TPB   = 512;   // 8 waves; 4 elements (one float4) per thread

// DPP ctrl encodings (gfx9/CDNA): row_shr:N = 0x110|N, row_bcast15 = 0x142,
// row_bcast31 = 0x143, wave_shr:1 = 0x138.
template<int CTRL, int RM>
__device__ __forceinline__ float dpp_mov_f(float old_v, float src) {
    return __int_as_float(__builtin_amdgcn_update_dpp(
        __float_as_int(old_v), __float_as_int(src), CTRL, RM, 0xf, false));
}

template<int CTRL, int RM>
__device__ __forceinline__ void scan_step(float& a, float& b) {
    const float a_up = dpp_mov_f<CTRL, RM>(1.0f, a);  // identity A = 1
    const float b_up = dpp_mov_f<CTRL, RM>(0.0f, b);  // identity B = 0
    b = __builtin_fmaf(a, b_up, b);   // apply current after previous
    a = a * a_up;
}

__global__ __launch_bounds__(TPB) void ifo_scan_kernel(
    const float* __restrict__ f,
    const float* __restrict__ z,
    const float* __restrict__ iin,
    float* __restrict__ out)
{
    const size_t base = (size_t)blockIdx.x * S_LEN;
    const int t    = threadIdx.x;
    const int lane = t & 63;
    const int wave = t >> 6;

    const float4 ff = reinterpret_cast<const float4*>(f   + base)[t];
    const float4 zz = reinterpret_cast<const float4*>(z   + base)[t];
    const float4 ii = reinterpret_cast<const float4*>(iin + base)[t];

    float4 xx;
    xx.x = ii.x * zz.x;
    xx.y = ii.y * zz.y;
    xx.z = ii.z * zz.z;
    xx.w = ii.w * zz.w;

    // Local chunk composition: h_out = A*h_in + B
    float A = ff.x, B = xx.x;
    A = ff.y * A;  B = ff.y * B + xx.y;
    A = ff.z * A;  B = ff.z * B + xx.z;
    A = ff.w * A;  B = ff.w * B + xx.w;

    // Wave-level inclusive scan of (A,B) under composition — DPP idiom.
    float a = A, b = B;
    scan_step<0x111, 0xf>(a, b);   // row_shr:1
    scan_step<0x112, 0xf>(a, b);   // row_shr:2
    scan_step<0x114, 0xf>(a, b);   // row_shr:4
    scan_step<0x118, 0xf>(a, b);   // row_shr:8
    scan_step<0x142, 0xa>(a, b);   // row_bcast15 -> rows 1,3
    scan_step<0x143, 0xc>(a, b);   // row_bcast31 -> rows 2,3

    // Cross-wave scan (8 waves) via LDS
    __shared__ float wa[8], wb[8];
    if (lane == 63) { wa[wave] = a; wb[wave] = b; }
    __syncthreads();

    float pb = 0.0f;                 // h entering this wave's span (h_{-1}=0)
    for (int w = 0; w < wave; ++w) {
        pb = wa[w] * pb + wb[w];
    }

    // Exclusive within-wave composition via wave_shr:1 (lane0 -> identity)
    const float ea = dpp_mov_f<0x138, 0xf>(1.0f, a);
    const float eb = dpp_mov_f<0x138, 0xf>(0.0f, b);

    // h entering this thread's chunk
    float h = ea * pb + eb;

    // Replay chunk with carried h; store
    float4 oo;
    h = ff.x * h + xx.x;  oo.x = h;
    h = ff.y * h + xx.y;  oo.y = h;
    h = ff.z * h + xx.z;  oo.z = h;
    h = ff.w * h + xx.w;  oo.w = h;
    reinterpret_cast<float4*>(out + base)[t] = oo;
}

extern "C" void kernel_launch(void* const* d_in, const int* in_sizes, int n_in,
                              void* d_out, int out_size, void* d_ws, size_t ws_size,
                              hipStream_t stream) {
    const float* f = (const float*)d_in[0];
    const float* z = (const float*)d_in[1];
    const float* i = (const float*)d_in[2];
    float* out = (float*)d_out;

    const int rows = out_size / S_LEN;   // B*H = 16384
    ifo_scan_kernel<<<rows, TPB, 0, stream>>>(f, z, i, out);
}